// Round 10
// baseline (244.984 us; speedup 1.0000x reference)
//
#include <hip/hip_runtime.h>
#include <hip/hip_bf16.h>

#define N_NODES 10000
#define KNEI    30
#define DIM     128
#define EDGES   (N_NODES * KNEI)

typedef __attribute__((ext_vector_type(4))) float  f32x4;
typedef __attribute__((ext_vector_type(8))) __bf16 bf16x8;
typedef __attribute__((ext_vector_type(4))) __bf16 bf16x4;

// packed bf16 weight offsets in d_ws (element units)
// CW1: K=256, N=256 combined [att_w1(e|hj part) | node_w1]   tiles: kt*16+nt
// CW2: K=128, N=256 combined [att_w2 | node_w2]              tiles: kt*16+nt
// NW3/HI/TH: K=128, N=128                                    tiles: kt*8+nt
#define OFF_CW1 0
#define OFF_CW2 65536
#define OFF_NW3 98304
#define OFF_HI  114688
#define OFF_TH  131072
#define TOT_TILES 288
#define YHI_BYTE_OFF (300 * 1024)   // f32 yhi[N][128] after weights

// Pack all weights (f32) into MFMA A-fragment order, bf16, one launch.
// Within a 512-elem tile: lane holds n = nt*16+(lane&15), k = kt*32+(lane>>4)*8+i.
__global__ __launch_bounds__(256) void repack_all(
    const float* __restrict__ aw1, const float* __restrict__ aw2,
    const float* __restrict__ nw1, const float* __restrict__ nw2,
    const float* __restrict__ nw3, const float* __restrict__ thw,
    __bf16* __restrict__ dst) {
    int t = blockIdx.x * 256 + threadIdx.x;
    if (t >= TOT_TILES * 512) return;
    int tile = t >> 9;
    int i    = t & 7;
    int lane = (t >> 3) & 63;
    int krow = ((lane >> 4) << 3) + i;   // 0..31
    int ncol = lane & 15;
    float v;
    if (tile < 128) {                    // CW1
        int kt = tile >> 4, nt = tile & 15;
        int k = kt * 32 + krow, n = nt * 16 + ncol;
        v = (n < 128) ? aw1[(128 + k) * 128 + n] : nw1[k * 128 + (n - 128)];
    } else if (tile < 192) {             // CW2
        int lt = tile - 128;
        int kt = lt >> 4, nt = lt & 15;
        int k = kt * 32 + krow, n = nt * 16 + ncol;
        v = (n < 128) ? aw2[k * 128 + n] : nw2[k * 128 + (n - 128)];
    } else {                             // NW3 / HI / TH (32 tiles each)
        int lt = tile & 31;
        int kt = lt >> 3, nt = lt & 7;
        int k = kt * 32 + krow, n = nt * 16 + ncol;
        const float* s = (tile < 224) ? nw3 : (tile < 256) ? aw1 : thw;
        v = s[k * 128 + n];
    }
    dst[t] = (__bf16)v;
}

// fast gelu (tanh form; abs err ~2e-4, << bf16 noise)
__device__ __forceinline__ float gelu_f(float x) {
    float u = 0.7978845608f * (x + 0.044715f * x * x * x);
    float t = 1.f - 2.f / (__expf(2.f * u) + 1.f);
    return 0.5f * x * (1.f + t);
}

__device__ __forceinline__ bf16x4 cvt4(float4 v) {
    bf16x4 r;
    r[0] = (__bf16)v.x; r[1] = (__bf16)v.y; r[2] = (__bf16)v.z; r[3] = (__bf16)v.w;
    return r;
}

// ---- generic 128->128 row GEMM (64 rows/block, 8 waves): out = in @ Wfrag (+bias) ----
__global__ __launch_bounds__(512) void mm128(const float* __restrict__ in,
                                             float* __restrict__ outp,
                                             const __bf16* __restrict__ wfrag,
                                             const float* __restrict__ bias) {
    __shared__ __bf16 sP[64 * 136];
    const int tid  = threadIdx.x;
    const int wv   = tid >> 6;
    const int lane = tid & 63;
    const int mrow = lane & 15;
    const int kgrp = lane >> 4;
    const int base = blockIdx.x * 64;

#pragma unroll
    for (int c = 0; c < 4; ++c) {
        int idx = c * 512 + tid;
        int m  = idx >> 5;
        int jv = idx & 31;
        int row = base + m;
        float4 v = make_float4(0.f, 0.f, 0.f, 0.f);
        if (row < N_NODES) v = *reinterpret_cast<const float4*>(in + (long)row * DIM + jv * 4);
        *reinterpret_cast<bf16x4*>(&sP[m * 136 + jv * 4]) = cvt4(v);
    }
    __syncthreads();

    f32x4 acc[4];
#pragma unroll
    for (int mf = 0; mf < 4; ++mf) acc[mf] = (f32x4){0.f, 0.f, 0.f, 0.f};
#pragma unroll
    for (int kt = 0; kt < 4; ++kt) {
        bf16x8 a = *reinterpret_cast<const bf16x8*>(wfrag + ((kt * 8 + wv) * 64 + lane) * 8);
        const int kb = kt * 32 + kgrp * 8;
#pragma unroll
        for (int mf = 0; mf < 4; ++mf) {
            bf16x8 b = *reinterpret_cast<const bf16x8*>(sP + (mf * 16 + mrow) * 136 + kb);
            acc[mf] = __builtin_amdgcn_mfma_f32_16x16x32_bf16(a, b, acc[mf], 0, 0, 0);
        }
    }
    const int nb = wv * 16 + kgrp * 4;
    float b0 = 0.f, b1 = 0.f, b2 = 0.f, b3 = 0.f;
    if (bias) { b0 = bias[nb]; b1 = bias[nb + 1]; b2 = bias[nb + 2]; b3 = bias[nb + 3]; }
#pragma unroll
    for (int mf = 0; mf < 4; ++mf) {
        int row = base + mf * 16 + mrow;
        if (row < N_NODES) {
            float4 o = make_float4(acc[mf][0] + b0, acc[mf][1] + b1,
                                   acc[mf][2] + b2, acc[mf][3] + b3);
            *reinterpret_cast<float4*>(outp + (long)row * DIM + nb) = o;
        }
    }
}

// ---- fused kernel: one block = 2 nodes, 1024 threads = 16 waves ----
// Wave (mh, nq): mh = wv>>3 selects node half (32 rows = 2 m-frags), nq = wv&7
// selects 32 combined feats (2 n-frags). acc[2][2] = 16 regs -> total unified
// regs ~48 (64-register class -> 8 waves/SIMD). Occupancy law measured over
// r2..r9: total VGPR+AGPR <= 64 -> ~84% occupancy; > 64 -> 44%. This is THE
// lever; keep per-wave register footprint <= 64.
// NOTE: launch_bounds min-waves that caps regs below need => ~75 MB spill
// (r3/r6/r9). (1024,4) caps at 128 - safe margin.
__global__ __launch_bounds__(1024, 4) void gnn_fused(
    const float* __restrict__ h, const float* __restrict__ e, const int* __restrict__ eidx,
    const float* __restrict__ yhi,
    const float* __restrict__ ab2, const float* __restrict__ aw3, const float* __restrict__ ab3,
    const float* __restrict__ nb1, const float* __restrict__ nb2, const float* __restrict__ nb3,
    const __bf16* __restrict__ wp, float* __restrict__ pre_out) {

    __shared__ __bf16 U[17408];      // S: 64 rows stride 264 (16896 used); later Y1@0 | Y2@8704 (stride 136); N2@0
    __shared__ float  sLP[4][64][4]; // logit partials from att waves nq=0..3
    __shared__ float  sW[64][4];     // softmax weights (rows 30,31,62,63 = 0)

    const int tid  = threadIdx.x;
    const int wv   = tid >> 6;       // 0..15
    const int mh   = wv >> 3;        // node half 0/1
    const int nq   = wv & 7;         // 32-feat quarter of combined N=256
    const int lane = tid & 63;
    const int mrow = lane & 15;
    const int kg   = lane >> 4;
    const int node0 = blockIdx.x * 2;
    const bool isatt = (nq < 4);

    // ---- P0: stage e|hj for both nodes (f32 -> bf16); pad rows 30,31,62,63 = 0 ----
#pragma unroll
    for (int c = 0; c < 2; ++c) {
        int idx = c * 1024 + tid;
        int m  = idx >> 5;   // row 0..63
        int jv = idx & 31;   // float4 col
        int nl = m >> 5;     // node-local 0/1
        int k  = m & 31;     // neighbor 0..31
        float4 ev = make_float4(0.f, 0.f, 0.f, 0.f), hjv = ev;
        if (k < KNEI) {
            long ge = (long)(node0 + nl) * KNEI + k;
            ev  = *reinterpret_cast<const float4*>(e + ge * DIM + jv * 4);
            int dstn = eidx[EDGES + ge];
            hjv = *reinterpret_cast<const float4*>(h + (long)dstn * DIM + jv * 4);
        }
        *reinterpret_cast<bf16x4*>(&U[m * 264 + jv * 4])       = cvt4(ev);
        *reinterpret_cast<bf16x4*>(&U[m * 264 + 128 + jv * 4]) = cvt4(hjv);
    }
    __syncthreads();   // b0

    const int row0 = mh * 32 + mrow;        // m-frag 0 row
    const int row1 = mh * 32 + 16 + mrow;   // m-frag 1 row

    f32x4 acc[2][2];   // [n-frag][m-frag]
    acc[0][0] = (f32x4){0.f,0.f,0.f,0.f}; acc[0][1] = (f32x4){0.f,0.f,0.f,0.f};
    acc[1][0] = (f32x4){0.f,0.f,0.f,0.f}; acc[1][1] = (f32x4){0.f,0.f,0.f,0.f};

    // ---- P1: combined layer-1 (K=256): [att1 | node1] over this node-half's [e|hj] ----
#pragma unroll
    for (int kt = 0; kt < 8; ++kt) {
        const int kb = kt * 32 + kg * 8;
        bf16x8 b0 = *reinterpret_cast<const bf16x8*>(U + row0 * 264 + kb);
        bf16x8 b1 = *reinterpret_cast<const bf16x8*>(U + row1 * 264 + kb);
        bf16x8 a0 = *reinterpret_cast<const bf16x8*>(wp + OFF_CW1 + (size_t)((kt * 16 + nq * 2 + 0) * 64 + lane) * 8);
        bf16x8 a1 = *reinterpret_cast<const bf16x8*>(wp + OFF_CW1 + (size_t)((kt * 16 + nq * 2 + 1) * 64 + lane) * 8);
        acc[0][0] = __builtin_amdgcn_mfma_f32_16x16x32_bf16(a0, b0, acc[0][0], 0, 0, 0);
        acc[0][1] = __builtin_amdgcn_mfma_f32_16x16x32_bf16(a0, b1, acc[0][1], 0, 0, 0);
        acc[1][0] = __builtin_amdgcn_mfma_f32_16x16x32_bf16(a1, b0, acc[1][0], 0, 0, 0);
        acc[1][1] = __builtin_amdgcn_mfma_f32_16x16x32_bf16(a1, b1, acc[1][1], 0, 0, 0);
    }
    __syncthreads();   // b1a: all S reads done; U re-carved as Y1@0 | Y2@8704

    // ---- E1: att waves -> relu(acc + yhi[node]) -> Y1 ; node waves -> gelu(acc + nb1) -> Y2 ----
    {
        __bf16* Y = U + (isatt ? 0 : 8704);
#pragma unroll
        for (int nt = 0; nt < 2; ++nt) {
            const int f = (isatt ? nq * 32 : (nq - 4) * 32) + nt * 16 + kg * 4;
            float4 ba = isatt ? *reinterpret_cast<const float4*>(yhi + (long)(node0 + mh) * DIM + f)
                              : *reinterpret_cast<const float4*>(nb1 + f);
            float bv[4] = {ba.x, ba.y, ba.z, ba.w};
#pragma unroll
            for (int mfl = 0; mfl < 2; ++mfl) {
                bf16x4 pk;
#pragma unroll
                for (int r = 0; r < 4; ++r) {
                    float v = acc[nt][mfl][r] + bv[r];
                    v = isatt ? fmaxf(v, 0.f) : gelu_f(v);
                    pk[r] = (__bf16)v;
                }
                *reinterpret_cast<bf16x4*>(Y + (mh * 32 + mfl * 16 + mrow) * 136 + f) = pk;
            }
        }
    }
    __syncthreads();   // b1b

    // ---- P2: combined layer-2 (K=128): att waves B=Y1, node waves B=Y2 ----
    acc[0][0] = (f32x4){0.f,0.f,0.f,0.f}; acc[0][1] = (f32x4){0.f,0.f,0.f,0.f};
    acc[1][0] = (f32x4){0.f,0.f,0.f,0.f}; acc[1][1] = (f32x4){0.f,0.f,0.f,0.f};
    {
        const __bf16* Yb = U + (isatt ? 0 : 8704);
#pragma unroll
        for (int kt = 0; kt < 4; ++kt) {
            const int kb = kt * 32 + kg * 8;
            bf16x8 b0 = *reinterpret_cast<const bf16x8*>(Yb + row0 * 136 + kb);
            bf16x8 b1 = *reinterpret_cast<const bf16x8*>(Yb + row1 * 136 + kb);
            bf16x8 a0 = *reinterpret_cast<const bf16x8*>(wp + OFF_CW2 + (size_t)((kt * 16 + nq * 2 + 0) * 64 + lane) * 8);
            bf16x8 a1 = *reinterpret_cast<const bf16x8*>(wp + OFF_CW2 + (size_t)((kt * 16 + nq * 2 + 1) * 64 + lane) * 8);
            acc[0][0] = __builtin_amdgcn_mfma_f32_16x16x32_bf16(a0, b0, acc[0][0], 0, 0, 0);
            acc[0][1] = __builtin_amdgcn_mfma_f32_16x16x32_bf16(a0, b1, acc[0][1], 0, 0, 0);
            acc[1][0] = __builtin_amdgcn_mfma_f32_16x16x32_bf16(a1, b0, acc[1][0], 0, 0, 0);
            acc[1][1] = __builtin_amdgcn_mfma_f32_16x16x32_bf16(a1, b1, acc[1][1], 0, 0, 0);
        }
    }

    // att waves: relu + fused logit layer (registers + sLP only), before b2a
    if (isatt) {
        float lp[2][4];
        lp[0][0]=lp[0][1]=lp[0][2]=lp[0][3]=0.f;
        lp[1][0]=lp[1][1]=lp[1][2]=lp[1][3]=0.f;
#pragma unroll
        for (int nt = 0; nt < 2; ++nt) {
            const int f = nq * 32 + nt * 16 + kg * 4;
            float b0 = ab2[f], b1 = ab2[f + 1], b2 = ab2[f + 2], b3 = ab2[f + 3];
            float4 w3v[4];
#pragma unroll
            for (int r = 0; r < 4; ++r)
                w3v[r] = *reinterpret_cast<const float4*>(aw3 + (f + r) * 4);
#pragma unroll
            for (int mfl = 0; mfl < 2; ++mfl) {
                float vv[4] = {acc[nt][mfl][0] + b0, acc[nt][mfl][1] + b1,
                               acc[nt][mfl][2] + b2, acc[nt][mfl][3] + b3};
#pragma unroll
                for (int r = 0; r < 4; ++r) {
                    float v = fmaxf(vv[r], 0.f);
                    lp[mfl][0] += v * w3v[r].x;
                    lp[mfl][1] += v * w3v[r].y;
                    lp[mfl][2] += v * w3v[r].z;
                    lp[mfl][3] += v * w3v[r].w;
                }
            }
        }
#pragma unroll
        for (int mfl = 0; mfl < 2; ++mfl)
#pragma unroll
            for (int hh = 0; hh < 4; ++hh) {
                lp[mfl][hh] += __shfl_xor(lp[mfl][hh], 16);
                lp[mfl][hh] += __shfl_xor(lp[mfl][hh], 32);
            }
        if (kg == 0) {
#pragma unroll
            for (int mfl = 0; mfl < 2; ++mfl) {
                float4 o = make_float4(lp[mfl][0], lp[mfl][1], lp[mfl][2], lp[mfl][3]);
                *reinterpret_cast<float4*>(&sLP[nq][mh * 32 + mfl * 16 + mrow][0]) = o;
            }
        }
    }
    __syncthreads();   // b2a: Y1 reads done; node waves may overwrite U[0:8704]

    // node waves: gelu(node2 + nb2) -> N2 = U@0
    if (!isatt) {
#pragma unroll
        for (int nt = 0; nt < 2; ++nt) {
            const int f = (nq - 4) * 32 + nt * 16 + kg * 4;
            float b0 = nb2[f], b1 = nb2[f + 1], b2 = nb2[f + 2], b3 = nb2[f + 3];
#pragma unroll
            for (int mfl = 0; mfl < 2; ++mfl) {
                float vv[4] = {acc[nt][mfl][0] + b0, acc[nt][mfl][1] + b1,
                               acc[nt][mfl][2] + b2, acc[nt][mfl][3] + b3};
                bf16x4 pk;
#pragma unroll
                for (int r = 0; r < 4; ++r) pk[r] = (__bf16)gelu_f(vv[r]);
                *reinterpret_cast<bf16x4*>(U + (mh * 32 + mfl * 16 + mrow) * 136 + f) = pk;
            }
        }
    }
    __syncthreads();   // b2b: N2 ready

    // ---- P3: node layer 3 (K=128, N=128) over N2; all 16 waves (n-tile = nq) ----
    f32x4 a3[2];       // [m-frag]
    a3[0] = (f32x4){0.f,0.f,0.f,0.f}; a3[1] = (f32x4){0.f,0.f,0.f,0.f};
#pragma unroll
    for (int kt = 0; kt < 4; ++kt) {
        const int kb = kt * 32 + kg * 8;
        bf16x8 b0 = *reinterpret_cast<const bf16x8*>(U + row0 * 136 + kb);
        bf16x8 b1 = *reinterpret_cast<const bf16x8*>(U + row1 * 136 + kb);
        bf16x8 a = *reinterpret_cast<const bf16x8*>(wp + OFF_NW3 + (size_t)((kt * 8 + nq) * 64 + lane) * 8);
        a3[0] = __builtin_amdgcn_mfma_f32_16x16x32_bf16(a, b0, a3[0], 0, 0, 0);
        a3[1] = __builtin_amdgcn_mfma_f32_16x16x32_bf16(a, b1, a3[1], 0, 0, 0);
    }
    // softmax: wave (mh, nq=0) lanes<32 handles node mh
    if (nq == 0 && lane < 32) {
        const int row = mh * 32 + lane;
        const float s = 0.17677669529f;  // 1/sqrt(32)
        float4 p = make_float4(ab3[0], ab3[1], ab3[2], ab3[3]);
#pragma unroll
        for (int w2 = 0; w2 < 4; ++w2) {
            float4 q = *reinterpret_cast<float4*>(&sLP[w2][row][0]);
            p.x += q.x; p.y += q.y; p.z += q.z; p.w += q.w;
        }
        float4 lg;
        if (lane < KNEI) lg = make_float4(p.x * s, p.y * s, p.z * s, p.w * s);
        else             lg = make_float4(-1e30f, -1e30f, -1e30f, -1e30f);
        float4 mx = lg;
#pragma unroll
        for (int msk = 1; msk <= 16; msk <<= 1) {
            mx.x = fmaxf(mx.x, __shfl_xor(mx.x, msk));
            mx.y = fmaxf(mx.y, __shfl_xor(mx.y, msk));
            mx.z = fmaxf(mx.z, __shfl_xor(mx.z, msk));
            mx.w = fmaxf(mx.w, __shfl_xor(mx.w, msk));
        }
        float4 ex = make_float4(__expf(lg.x - mx.x), __expf(lg.y - mx.y),
                                __expf(lg.z - mx.z), __expf(lg.w - mx.w));
        float4 sm = ex;
#pragma unroll
        for (int msk = 1; msk <= 16; msk <<= 1) {
            sm.x += __shfl_xor(sm.x, msk);
            sm.y += __shfl_xor(sm.y, msk);
            sm.z += __shfl_xor(sm.z, msk);
            sm.w += __shfl_xor(sm.w, msk);
        }
        float4 w = make_float4(ex.x / sm.x, ex.y / sm.y, ex.z / sm.z, ex.w / sm.w);
        *reinterpret_cast<float4*>(&sW[row][0]) = w;   // pad rows -> 0
    }
    __syncthreads();   // b3: sW visible

    // ---- P4: fused aggregation: pre[node0+mh][16nq..] = sum_m w[m]*(V + nb3) ----
    {
        const int head = nq >> 1;
        float wg0 = sW[row0][head];
        float wg1 = sW[row1][head];
        float part[4];
#pragma unroll
        for (int r = 0; r < 4; ++r)
            part[r] = wg0 * a3[0][r] + wg1 * a3[1][r];
#pragma unroll
        for (int msk = 1; msk <= 8; msk <<= 1)
#pragma unroll
            for (int r = 0; r < 4; ++r)
                part[r] += __shfl_xor(part[r], msk);
        if (mrow == 0) {
            const int nb = nq * 16 + kg * 4;
            float4 o = make_float4(part[0] + nb3[nb],     part[1] + nb3[nb + 1],
                                   part[2] + nb3[nb + 2], part[3] + nb3[nb + 3]);
            *reinterpret_cast<float4*>(pre_out + (long)(node0 + mh) * DIM + nb) = o;
        }
    }
}

extern "C" void kernel_launch(void* const* d_in, const int* in_sizes, int n_in,
                              void* d_out, int out_size, void* d_ws, size_t ws_size,
                              hipStream_t stream) {
    const float* h   = (const float*)d_in[0];
    const float* e   = (const float*)d_in[1];
    const int*   ei  = (const int*)d_in[2];
    const float* aw1 = (const float*)d_in[3];
    const float* ab1 = (const float*)d_in[4];
    const float* aw2 = (const float*)d_in[5];
    const float* ab2 = (const float*)d_in[6];
    const float* aw3 = (const float*)d_in[7];
    const float* ab3 = (const float*)d_in[8];
    const float* nw1 = (const float*)d_in[9];
    const float* nb1 = (const float*)d_in[10];
    const float* nw2 = (const float*)d_in[11];
    const float* nb2 = (const float*)d_in[12];
    const float* nw3 = (const float*)d_in[13];
    const float* nb3 = (const float*)d_in[14];
    const float* thw = (const float*)d_in[15];
    float* out = (float*)d_out;
    __bf16* wp = (__bf16*)d_ws;
    float* yhi = (float*)((char*)d_ws + YHI_BYTE_OFF);

    // all-weight repack (f32 -> bf16 MFMA-fragment order), one launch
    repack_all<<<TOT_TILES * 2, 256, 0, stream>>>(aw1, aw2, nw1, nw2, nw3, thw, wp);

    const int nblk = (N_NODES + 63) / 64;
    // yhi = h @ att_w1[0:128,:] + ab1   (hi part of att layer 1, per node)
    mm128<<<nblk, 512, 0, stream>>>(h, yhi, wp + OFF_HI, ab1);

    gnn_fused<<<N_NODES / 2, 1024, 0, stream>>>(h, e, ei, yhi, ab2, aw3, ab3,
                                                nb1, nb2, nb3, wp, out);
    // out = pre @ to_h_w (in-place)
    mm128<<<nblk, 512, 0, stream>>>(out, out, wp + OFF_TH, nullptr);
}

// Round 11
// 179.590 us; speedup vs baseline: 1.3641x; 1.3641x over previous
//
#include <hip/hip_runtime.h>
#include <hip/hip_bf16.h>

#define N_NODES 10000
#define KNEI    30
#define DIM     128
#define EDGES   (N_NODES * KNEI)

typedef __attribute__((ext_vector_type(4))) float  f32x4;
typedef __attribute__((ext_vector_type(8))) __bf16 bf16x8;
typedef __attribute__((ext_vector_type(4))) __bf16 bf16x4;

// packed bf16 weight offsets in d_ws (element units); per-matrix fragment tiles
// AW1 (K=384, kt0..3 = hi part, kt4..11 = e|hj), others K=128/256, Ntiles=8.
#define OFF_AW1 0        // 96 tiles
#define OFF_AW2 49152    // 32 tiles
#define OFF_NW1 65536    // 64 tiles
#define OFF_NW2 98304    // 32 tiles
#define OFF_NW3 114688   // 32 tiles
#define OFF_TH  131072   // 32 tiles
#define TOT_TILES 288
#define YHI_BYTE_OFF (300 * 1024)   // f32 yhi[N][128] after weights

// Pack all weights (f32) into MFMA A-fragment order, bf16, one launch.
// tile = kt*8+nt; lane holds n = nt*16+(lane&15), k = kt*32+(lane>>4)*8+i.
__global__ __launch_bounds__(256) void repack_all(
    const float* __restrict__ aw1, const float* __restrict__ aw2,
    const float* __restrict__ nw1, const float* __restrict__ nw2,
    const float* __restrict__ nw3, const float* __restrict__ thw,
    __bf16* __restrict__ dst) {
    int t = blockIdx.x * 256 + threadIdx.x;
    if (t >= TOT_TILES * 512) return;
    int tile = t >> 9;
    int i    = t & 7;
    int lane = (t >> 3) & 63;
    const float* src; int lt;
    if      (tile < 96)  { src = aw1; lt = tile; }        // K=384
    else if (tile < 128) { src = aw2; lt = tile - 96; }
    else if (tile < 192) { src = nw1; lt = tile - 128; }  // K=256
    else if (tile < 224) { src = nw2; lt = tile - 192; }
    else if (tile < 256) { src = nw3; lt = tile - 224; }
    else                 { src = thw; lt = tile - 256; }
    int nt = lt & 7;
    int kt = lt >> 3;
    int k = kt * 32 + ((lane >> 4) << 3) + i;
    int n = nt * 16 + (lane & 15);
    dst[t] = (__bf16)src[k * DIM + n];
}

// fast gelu (tanh form; abs err ~2e-4, << bf16 noise)
__device__ __forceinline__ float gelu_f(float x) {
    float u = 0.7978845608f * (x + 0.044715f * x * x * x);
    float t = 1.f - 2.f / (__expf(2.f * u) + 1.f);
    return 0.5f * x * (1.f + t);
}

__device__ __forceinline__ bf16x4 cvt4(float4 v) {
    bf16x4 r;
    r[0] = (__bf16)v.x; r[1] = (__bf16)v.y; r[2] = (__bf16)v.z; r[3] = (__bf16)v.w;
    return r;
}

// 8-wave LDS-B MFMA: 2 m-frags (32 rows), wave owns 16 n-features (nt = wv).
__device__ __forceinline__ void mm_lds(f32x4 acc[2], const __bf16* __restrict__ wfrag,
                                       const __bf16* x, int sx, int nkt,
                                       int wv, int lane) {
    const int mrow = lane & 15;
    const int kgrp = (lane >> 4) & 3;
#pragma unroll
    for (int kt = 0; kt < nkt; ++kt) {
        bf16x8 a = *reinterpret_cast<const bf16x8*>(wfrag + ((kt * 8 + wv) * 64 + lane) * 8);
        const int kb = kt * 32 + kgrp * 8;
#pragma unroll
        for (int mf = 0; mf < 2; ++mf) {
            bf16x8 b = *reinterpret_cast<const bf16x8*>(x + (mf * 16 + mrow) * sx + kb);
            acc[mf] = __builtin_amdgcn_mfma_f32_16x16x32_bf16(a, b, acc[mf], 0, 0, 0);
        }
    }
}

// actmode: 0 = relu, 1 = gelu. bias may be a per-node yhi row.
__device__ __forceinline__ void store_act(f32x4 acc[2], const float* __restrict__ bias,
                                          __bf16* y, int sy, int actmode,
                                          int wv, int lane) {
    const int mrow = lane & 15;
    const int kgrp = (lane >> 4) & 3;
    const int nb = wv * 16 + kgrp * 4;
    float b0 = bias[nb], b1 = bias[nb + 1], b2 = bias[nb + 2], b3 = bias[nb + 3];
#pragma unroll
    for (int mf = 0; mf < 2; ++mf) {
        bf16x4 pk;
        float vv[4] = {acc[mf][0] + b0, acc[mf][1] + b1, acc[mf][2] + b2, acc[mf][3] + b3};
#pragma unroll
        for (int r = 0; r < 4; ++r) {
            float v = vv[r];
            v = actmode == 0 ? fmaxf(v, 0.f) : gelu_f(v);
            pk[r] = (__bf16)v;
        }
        *reinterpret_cast<bf16x4*>(y + (mf * 16 + mrow) * sy + nb) = pk;
    }
}

#define ZERO2(A) do { A[0] = (f32x4){0.f,0.f,0.f,0.f}; A[1] = (f32x4){0.f,0.f,0.f,0.f}; } while (0)

// ---- generic 128->128 row GEMM (64 rows/block, 8 waves): out = in @ Wfrag (+bias) ----
__global__ __launch_bounds__(512) void mm128(const float* __restrict__ in,
                                             float* __restrict__ outp,
                                             const __bf16* __restrict__ wfrag,
                                             const float* __restrict__ bias) {
    __shared__ __bf16 sP[64 * 136];
    const int tid  = threadIdx.x;
    const int wv   = tid >> 6;
    const int lane = tid & 63;
    const int mrow = lane & 15;
    const int kgrp = lane >> 4;
    const int base = blockIdx.x * 64;

#pragma unroll
    for (int c = 0; c < 4; ++c) {
        int idx = c * 512 + tid;
        int m  = idx >> 5;
        int jv = idx & 31;
        int row = base + m;
        float4 v = make_float4(0.f, 0.f, 0.f, 0.f);
        if (row < N_NODES) v = *reinterpret_cast<const float4*>(in + (long)row * DIM + jv * 4);
        *reinterpret_cast<bf16x4*>(&sP[m * 136 + jv * 4]) = cvt4(v);
    }
    __syncthreads();

    f32x4 acc[4];
#pragma unroll
    for (int mf = 0; mf < 4; ++mf) acc[mf] = (f32x4){0.f, 0.f, 0.f, 0.f};
#pragma unroll
    for (int kt = 0; kt < 4; ++kt) {
        bf16x8 a = *reinterpret_cast<const bf16x8*>(wfrag + ((kt * 8 + wv) * 64 + lane) * 8);
        const int kb = kt * 32 + kgrp * 8;
#pragma unroll
        for (int mf = 0; mf < 4; ++mf) {
            bf16x8 b = *reinterpret_cast<const bf16x8*>(sP + (mf * 16 + mrow) * 136 + kb);
            acc[mf] = __builtin_amdgcn_mfma_f32_16x16x32_bf16(a, b, acc[mf], 0, 0, 0);
        }
    }
    const int nb = wv * 16 + kgrp * 4;
    float b0 = 0.f, b1 = 0.f, b2 = 0.f, b3 = 0.f;
    if (bias) { b0 = bias[nb]; b1 = bias[nb + 1]; b2 = bias[nb + 2]; b3 = bias[nb + 3]; }
#pragma unroll
    for (int mf = 0; mf < 4; ++mf) {
        int row = base + mf * 16 + mrow;
        if (row < N_NODES) {
            float4 o = make_float4(acc[mf][0] + b0, acc[mf][1] + b1,
                                   acc[mf][2] + b2, acc[mf][3] + b3);
            *reinterpret_cast<float4*>(outp + (long)row * DIM + nb) = o;
        }
    }
}

// ---- fused kernel: one block = 1 node (30 edges padded to 32), 512 thr = 8 waves ----
// r4's layout: wave wv owns n-features [wv*16, wv*16+16) (acc[2] = 8 regs).
// Occupancy law (r1..r10 measured): waves/SIMD ~ floor(256/VGPR); VGPR<=32 is
// the only config reaching ~8/SIMD (84%). Keep per-wave registers MINIMAL.
// Aggregation fused into node-L3 epilogue (V never touches LDS).
__global__ __launch_bounds__(512, 4) void gnn_fused(
    const float* __restrict__ h, const float* __restrict__ e, const int* __restrict__ eidx,
    const float* __restrict__ yhi,
    const float* __restrict__ ab2, const float* __restrict__ aw3, const float* __restrict__ ab3,
    const float* __restrict__ nb1, const float* __restrict__ nb2, const float* __restrict__ nb3,
    const __bf16* __restrict__ wp, float* __restrict__ pre_out) {

    __shared__ __bf16 S[32 * 264];      // [m][0:128)=e, [128:256)=hj (stride 264)
    __shared__ __bf16 Y1[32 * 136];     // att1-out -> node2-out
    __shared__ __bf16 Y2[32 * 136];     // node1-out
    __shared__ float  sLogW[8][32][4];  // per-wave logit partials; [0] = final logits
    __shared__ float  sW[32][4];        // softmax weights (rows 30/31 = 0)

    const int tid  = threadIdx.x;
    const int wv   = tid >> 6;
    const int lane = tid & 63;
    const int mrow = lane & 15;
    const int kg   = (lane >> 4) & 3;
    const int node = blockIdx.x;
    const long ebase = (long)node * KNEI;

    // ---- P0: stage e|hj (f32 -> bf16), pad rows 30/31 = 0 ----
#pragma unroll
    for (int c = 0; c < 2; ++c) {
        int idx = c * 512 + tid;
        int m  = idx >> 5;   // row 0..31
        int jv = idx & 31;   // float4 col
        float4 ev = make_float4(0.f, 0.f, 0.f, 0.f), hjv = ev;
        if (m < KNEI) {
            long ge = ebase + m;
            ev  = *reinterpret_cast<const float4*>(e + ge * DIM + jv * 4);
            int dstn = eidx[EDGES + ge];
            hjv = *reinterpret_cast<const float4*>(h + (long)dstn * DIM + jv * 4);
        }
        *reinterpret_cast<bf16x4*>(&S[m * 264 + jv * 4])       = cvt4(ev);
        *reinterpret_cast<bf16x4*>(&S[m * 264 + 128 + jv * 4]) = cvt4(hjv);
    }
    __syncthreads();   // b0

    f32x4 acc[2];

    // ---- P1: att layer 1: [e|hj] K=256 MFMA + yhi-as-bias -> relu -> Y1 ----
    ZERO2(acc);
    mm_lds(acc, wp + OFF_AW1 + 16384, S, 264, 8, wv, lane);
    store_act(acc, yhi + (long)node * DIM, Y1, 136, 0, wv, lane);
    __syncthreads();   // b1

    // ---- P2: att layer 2 + fused logit layer; node layer 1 ----
    {
        ZERO2(acc);
        mm_lds(acc, wp + OFF_AW2, Y1, 136, 4, wv, lane);
        const int nb = wv * 16 + kg * 4;
        float b0 = ab2[nb], b1 = ab2[nb + 1], b2 = ab2[nb + 2], b3 = ab2[nb + 3];
        float4 w3v[4];
#pragma unroll
        for (int r = 0; r < 4; ++r)
            w3v[r] = *reinterpret_cast<const float4*>(aw3 + (nb + r) * 4);
        float lp[2][4];
#pragma unroll
        for (int mf = 0; mf < 2; ++mf) {
            lp[mf][0] = lp[mf][1] = lp[mf][2] = lp[mf][3] = 0.f;
            float vv[4] = {acc[mf][0] + b0, acc[mf][1] + b1, acc[mf][2] + b2, acc[mf][3] + b3};
#pragma unroll
            for (int r = 0; r < 4; ++r) {
                float v = fmaxf(vv[r], 0.f);
                lp[mf][0] += v * w3v[r].x;
                lp[mf][1] += v * w3v[r].y;
                lp[mf][2] += v * w3v[r].z;
                lp[mf][3] += v * w3v[r].w;
            }
        }
#pragma unroll
        for (int mf = 0; mf < 2; ++mf)
#pragma unroll
            for (int hh = 0; hh < 4; ++hh) {
                lp[mf][hh] += __shfl_xor(lp[mf][hh], 16);
                lp[mf][hh] += __shfl_xor(lp[mf][hh], 32);
            }
        if (kg == 0 && lane < 16) {
#pragma unroll
            for (int mf = 0; mf < 2; ++mf) {
                float4 o = make_float4(lp[mf][0], lp[mf][1], lp[mf][2], lp[mf][3]);
                *reinterpret_cast<float4*>(&sLogW[wv][mf * 16 + mrow][0]) = o;
            }
        }
    }
    ZERO2(acc);
    mm_lds(acc, wp + OFF_NW1, S, 264, 8, wv, lane);   // node L1: [e|hj] K=256
    store_act(acc, nb1, Y2, 136, 1, wv, lane);
    __syncthreads();   // b2

    // ---- P3: logit cross-wave reduce; node layer 2: Y2 -> Y1 ----
    if (tid < 128) {
        int m = tid >> 2, hh = tid & 3;
        float s = ab3[hh];
#pragma unroll
        for (int w = 0; w < 8; ++w) s += sLogW[w][m][hh];
        sLogW[0][m][hh] = s * 0.17677669529f;   // /sqrt(32)
    }
    ZERO2(acc);
    mm_lds(acc, wp + OFF_NW2, Y2, 136, 4, wv, lane);
    store_act(acc, nb2, Y1, 136, 1, wv, lane);
    __syncthreads();   // b3

    // ---- P4: node layer 3 -> V stays in acc; wave-parallel softmax -> sW ----
    ZERO2(acc);
    mm_lds(acc, wp + OFF_NW3, Y1, 136, 4, wv, lane);
    if (wv == 0 && lane < 32) {
        float4 lg = (lane < KNEI) ? *reinterpret_cast<float4*>(&sLogW[0][lane][0])
                                  : make_float4(-1e30f, -1e30f, -1e30f, -1e30f);
        float4 mx = lg;
#pragma unroll
        for (int msk = 1; msk <= 16; msk <<= 1) {
            mx.x = fmaxf(mx.x, __shfl_xor(mx.x, msk));
            mx.y = fmaxf(mx.y, __shfl_xor(mx.y, msk));
            mx.z = fmaxf(mx.z, __shfl_xor(mx.z, msk));
            mx.w = fmaxf(mx.w, __shfl_xor(mx.w, msk));
        }
        float4 ex = make_float4(__expf(lg.x - mx.x), __expf(lg.y - mx.y),
                                __expf(lg.z - mx.z), __expf(lg.w - mx.w));
        float4 sm = ex;
#pragma unroll
        for (int msk = 1; msk <= 16; msk <<= 1) {
            sm.x += __shfl_xor(sm.x, msk);
            sm.y += __shfl_xor(sm.y, msk);
            sm.z += __shfl_xor(sm.z, msk);
            sm.w += __shfl_xor(sm.w, msk);
        }
        float4 w = make_float4(ex.x / sm.x, ex.y / sm.y, ex.z / sm.z, ex.w / sm.w);
        *reinterpret_cast<float4*>(&sW[lane][0]) = w;   // rows 30/31 -> 0 (exp(-inf))
    }
    __syncthreads();   // b4: sW visible

    // ---- P5: fused aggregation epilogue: pre[node][n] = sum_m w[m]*(V+nb3) ----
    {
        const int hh = wv >> 1;           // head of this wave's 16-feature slice
        float wgt0 = sW[mrow][hh];        // edge m = mrow      (mf=0)
        float wgt1 = sW[16 + mrow][hh];   // edge m = 16 + mrow (mf=1)
        float part[4];
#pragma unroll
        for (int r = 0; r < 4; ++r)
            part[r] = wgt0 * acc[0][r] + wgt1 * acc[1][r];
#pragma unroll
        for (int msk = 1; msk <= 8; msk <<= 1)
#pragma unroll
            for (int r = 0; r < 4; ++r)
                part[r] += __shfl_xor(part[r], msk);
        if (mrow == 0) {                  // lanes 0,16,32,48 -> kg 0..3
            const int nb = wv * 16 + kg * 4;
            float4 o = make_float4(part[0] + nb3[nb],     part[1] + nb3[nb + 1],
                                   part[2] + nb3[nb + 2], part[3] + nb3[nb + 3]);
            *reinterpret_cast<float4*>(pre_out + (long)node * DIM + nb) = o;
        }
    }
}

extern "C" void kernel_launch(void* const* d_in, const int* in_sizes, int n_in,
                              void* d_out, int out_size, void* d_ws, size_t ws_size,
                              hipStream_t stream) {
    const float* h   = (const float*)d_in[0];
    const float* e   = (const float*)d_in[1];
    const int*   ei  = (const int*)d_in[2];
    const float* aw1 = (const float*)d_in[3];
    const float* ab1 = (const float*)d_in[4];
    const float* aw2 = (const float*)d_in[5];
    const float* ab2 = (const float*)d_in[6];
    const float* aw3 = (const float*)d_in[7];
    const float* ab3 = (const float*)d_in[8];
    const float* nw1 = (const float*)d_in[9];
    const float* nb1 = (const float*)d_in[10];
    const float* nw2 = (const float*)d_in[11];
    const float* nb2 = (const float*)d_in[12];
    const float* nw3 = (const float*)d_in[13];
    const float* nb3 = (const float*)d_in[14];
    const float* thw = (const float*)d_in[15];
    float* out = (float*)d_out;
    __bf16* wp = (__bf16*)d_ws;
    float* yhi = (float*)((char*)d_ws + YHI_BYTE_OFF);

    // all-weight repack (f32 -> bf16 MFMA-fragment order), one launch
    repack_all<<<TOT_TILES * 2, 256, 0, stream>>>(aw1, aw2, nw1, nw2, nw3, thw, wp);

    const int nblk = (N_NODES + 63) / 64;
    // yhi = h @ att_w1[0:128,:] + ab1   (hi part of att layer 1, per node)
    mm128<<<nblk, 512, 0, stream>>>(h, yhi, wp + OFF_AW1, ab1);

    gnn_fused<<<N_NODES, 512, 0, stream>>>(h, e, ei, yhi, ab2, aw3, ab3,
                                           nb1, nb2, nb3, wp, out);
    // out = pre @ to_h_w (in-place)
    mm128<<<nblk, 512, 0, stream>>>(out, out, wp + OFF_TH, nullptr);
}

// Round 12
// 153.865 us; speedup vs baseline: 1.5922x; 1.1672x over previous
//
#include <hip/hip_runtime.h>
#include <hip/hip_bf16.h>

#define N_NODES 10000
#define KNEI    30
#define DIM     128
#define EDGES   (N_NODES * KNEI)

typedef __attribute__((ext_vector_type(4))) float  f32x4;
typedef __attribute__((ext_vector_type(8))) __bf16 bf16x8;
typedef __attribute__((ext_vector_type(4))) __bf16 bf16x4;

// packed bf16 weight offsets in d_ws (element units); per-matrix fragment tiles
// AW1 (K=384, kt0..3 = hi part, kt4..11 = e|hj), others K=128/256, Ntiles=8.
#define OFF_AW1 0        // 96 tiles
#define OFF_AW2 49152    // 32 tiles
#define OFF_NW1 65536    // 64 tiles
#define OFF_NW2 98304    // 32 tiles
#define OFF_NW3 114688   // 32 tiles
#define OFF_TH  131072   // 32 tiles
#define TOT_TILES 288
#define YHI_BYTE_OFF (300 * 1024)   // f32 yhi[N][128] after weights

// Pack all weights (f32) into MFMA A-fragment order, bf16, one launch.
// tile = kt*8+nt; lane holds n = nt*16+(lane&15), k = kt*32+(lane>>4)*8+i.
__global__ __launch_bounds__(256) void repack_all(
    const float* __restrict__ aw1, const float* __restrict__ aw2,
    const float* __restrict__ nw1, const float* __restrict__ nw2,
    const float* __restrict__ nw3, const float* __restrict__ thw,
    __bf16* __restrict__ dst) {
    int t = blockIdx.x * 256 + threadIdx.x;
    if (t >= TOT_TILES * 512) return;
    int tile = t >> 9;
    int i    = t & 7;
    int lane = (t >> 3) & 63;
    const float* src; int lt;
    if      (tile < 96)  { src = aw1; lt = tile; }        // K=384
    else if (tile < 128) { src = aw2; lt = tile - 96; }
    else if (tile < 192) { src = nw1; lt = tile - 128; }  // K=256
    else if (tile < 224) { src = nw2; lt = tile - 192; }
    else if (tile < 256) { src = nw3; lt = tile - 224; }
    else                 { src = thw; lt = tile - 256; }
    int nt = lt & 7;
    int kt = lt >> 3;
    int k = kt * 32 + ((lane >> 4) << 3) + i;
    int n = nt * 16 + (lane & 15);
    dst[t] = (__bf16)src[k * DIM + n];
}

// fast gelu: exact rewrite 0.5x(1+tanh(u)) = x*sigmoid(2u) = x - x/(exp(2u)+1)
// (~8 VALU incl native rcp; same tanh-approx error ~2e-4 << bf16 noise)
__device__ __forceinline__ float gelu_f(float x) {
    float y = x * fmaf(0.0713548163f, x * x, 1.5957691216f);  // 2u
    float r = __builtin_amdgcn_rcpf(__expf(y) + 1.f);
    return x - x * r;
}

__device__ __forceinline__ bf16x4 cvt4(float4 v) {
    bf16x4 r;
    r[0] = (__bf16)v.x; r[1] = (__bf16)v.y; r[2] = (__bf16)v.z; r[3] = (__bf16)v.w;
    return r;
}

// actmode: 0 = relu, 1 = gelu. bias may be a per-node yhi row.
__device__ __forceinline__ void store_act(f32x4 acc[2], const float* __restrict__ bias,
                                          __bf16* y, int sy, int actmode,
                                          int wv, int lane) {
    const int mrow = lane & 15;
    const int kgrp = (lane >> 4) & 3;
    const int nb = wv * 16 + kgrp * 4;
    float b0 = bias[nb], b1 = bias[nb + 1], b2 = bias[nb + 2], b3 = bias[nb + 3];
#pragma unroll
    for (int mf = 0; mf < 2; ++mf) {
        bf16x4 pk;
        float vv[4] = {acc[mf][0] + b0, acc[mf][1] + b1, acc[mf][2] + b2, acc[mf][3] + b3};
#pragma unroll
        for (int r = 0; r < 4; ++r) {
            float v = vv[r];
            v = actmode == 0 ? fmaxf(v, 0.f) : gelu_f(v);
            pk[r] = (__bf16)v;
        }
        *reinterpret_cast<bf16x4*>(y + (mf * 16 + mrow) * sy + nb) = pk;
    }
}

#define ZERO2(A) do { A[0] = (f32x4){0.f,0.f,0.f,0.f}; A[1] = (f32x4){0.f,0.f,0.f,0.f}; } while (0)

// ---- generic 128->128 row GEMM (64 rows/block, 8 waves): out = in @ Wfrag (+bias) ----
__global__ __launch_bounds__(512) void mm128(const float* __restrict__ in,
                                             float* __restrict__ outp,
                                             const __bf16* __restrict__ wfrag,
                                             const float* __restrict__ bias) {
    __shared__ __bf16 sP[64 * 136];
    const int tid  = threadIdx.x;
    const int wv   = tid >> 6;
    const int lane = tid & 63;
    const int mrow = lane & 15;
    const int kgrp = lane >> 4;
    const int base = blockIdx.x * 64;

#pragma unroll
    for (int c = 0; c < 4; ++c) {
        int idx = c * 512 + tid;
        int m  = idx >> 5;
        int jv = idx & 31;
        int row = base + m;
        float4 v = make_float4(0.f, 0.f, 0.f, 0.f);
        if (row < N_NODES) v = *reinterpret_cast<const float4*>(in + (long)row * DIM + jv * 4);
        *reinterpret_cast<bf16x4*>(&sP[m * 136 + jv * 4]) = cvt4(v);
    }
    __syncthreads();

    f32x4 acc[4];
#pragma unroll
    for (int mf = 0; mf < 4; ++mf) acc[mf] = (f32x4){0.f, 0.f, 0.f, 0.f};
#pragma unroll
    for (int kt = 0; kt < 4; ++kt) {
        bf16x8 a = *reinterpret_cast<const bf16x8*>(wfrag + ((kt * 8 + wv) * 64 + lane) * 8);
        const int kb = kt * 32 + kgrp * 8;
#pragma unroll
        for (int mf = 0; mf < 4; ++mf) {
            bf16x8 b = *reinterpret_cast<const bf16x8*>(sP + (mf * 16 + mrow) * 136 + kb);
            acc[mf] = __builtin_amdgcn_mfma_f32_16x16x32_bf16(a, b, acc[mf], 0, 0, 0);
        }
    }
    const int nb = wv * 16 + kgrp * 4;
    float b0 = 0.f, b1 = 0.f, b2 = 0.f, b3 = 0.f;
    if (bias) { b0 = bias[nb]; b1 = bias[nb + 1]; b2 = bias[nb + 2]; b3 = bias[nb + 3]; }
#pragma unroll
    for (int mf = 0; mf < 4; ++mf) {
        int row = base + mf * 16 + mrow;
        if (row < N_NODES) {
            float4 o = make_float4(acc[mf][0] + b0, acc[mf][1] + b1,
                                   acc[mf][2] + b2, acc[mf][3] + b3);
            *reinterpret_cast<float4*>(outp + (long)row * DIM + nb) = o;
        }
    }
}

// ---- fused kernel: one block = 1 node (30 edges padded to 32), 512 thr = 8 waves ----
// 4 barriers. P1 = MERGED layer-1 (att1 + node1 share each ds_read of S).
// P2 = wave-split layer-2 (waves 0-3: att2+fused logits; waves 4-7: node2 -> S').
// P3 = node3 (V in regs) with wave-0 softmax (reduce+normalize, wave-internal order).
// P4 = fused aggregation epilogue.
// Occupancy law (r1..r11 measured): waves/SIMD ~ floor(256/VGPR), 512-thr blocks.
// VGPR target <= 42 for 6/SIMD; keep per-wave register footprint minimal.
__global__ __launch_bounds__(512, 4) void gnn_fused(
    const float* __restrict__ h, const float* __restrict__ e, const int* __restrict__ eidx,
    const float* __restrict__ yhi,
    const float* __restrict__ ab2, const float* __restrict__ aw3, const float* __restrict__ ab3,
    const float* __restrict__ nb1, const float* __restrict__ nb2, const float* __restrict__ nb3,
    const __bf16* __restrict__ wp, float* __restrict__ pre_out) {

    __shared__ __bf16 S[32 * 264];    // e|hj (stride 264); dead after P1; reused as S' = node2-out (stride 136)
    __shared__ __bf16 Y1[32 * 136];   // att1-out
    __shared__ __bf16 Y2[32 * 136];   // node1-out
    __shared__ float  sLP[4][32][4];  // att-wave logit partials
    __shared__ float  sW[32][4];      // softmax weights (rows 30/31 = 0)

    const int tid  = threadIdx.x;
    const int wv   = tid >> 6;
    const int lane = tid & 63;
    const int mrow = lane & 15;
    const int kg   = (lane >> 4) & 3;
    const int node = blockIdx.x;
    const long ebase = (long)node * KNEI;

    // ---- P0: stage e|hj (f32 -> bf16), pad rows 30/31 = 0 ----
#pragma unroll
    for (int c = 0; c < 2; ++c) {
        int idx = c * 512 + tid;
        int m  = idx >> 5;   // row 0..31
        int jv = idx & 31;   // float4 col
        float4 ev = make_float4(0.f, 0.f, 0.f, 0.f), hjv = ev;
        if (m < KNEI) {
            long ge = ebase + m;
            ev  = *reinterpret_cast<const float4*>(e + ge * DIM + jv * 4);
            int dstn = eidx[EDGES + ge];
            hjv = *reinterpret_cast<const float4*>(h + (long)dstn * DIM + jv * 4);
        }
        *reinterpret_cast<bf16x4*>(&S[m * 264 + jv * 4])       = cvt4(ev);
        *reinterpret_cast<bf16x4*>(&S[m * 264 + 128 + jv * 4]) = cvt4(hjv);
    }
    __syncthreads();   // b0

    // ---- P1: MERGED layer-1 (K=256): att1 & node1 share S b-reads ----
    {
        f32x4 aa[2], an[2];
        ZERO2(aa); ZERO2(an);
        const __bf16* wA = wp + OFF_AW1 + 16384;   // att_w1 e|hj part (kt 4..11)
        const __bf16* wN = wp + OFF_NW1;
#pragma unroll
        for (int kt = 0; kt < 8; ++kt) {
            const int kb = kt * 32 + kg * 8;
            bf16x8 b0 = *reinterpret_cast<const bf16x8*>(S + mrow * 264 + kb);
            bf16x8 b1 = *reinterpret_cast<const bf16x8*>(S + (16 + mrow) * 264 + kb);
            bf16x8 a0 = *reinterpret_cast<const bf16x8*>(wA + ((kt * 8 + wv) * 64 + lane) * 8);
            aa[0] = __builtin_amdgcn_mfma_f32_16x16x32_bf16(a0, b0, aa[0], 0, 0, 0);
            aa[1] = __builtin_amdgcn_mfma_f32_16x16x32_bf16(a0, b1, aa[1], 0, 0, 0);
            bf16x8 a1 = *reinterpret_cast<const bf16x8*>(wN + ((kt * 8 + wv) * 64 + lane) * 8);
            an[0] = __builtin_amdgcn_mfma_f32_16x16x32_bf16(a1, b0, an[0], 0, 0, 0);
            an[1] = __builtin_amdgcn_mfma_f32_16x16x32_bf16(a1, b1, an[1], 0, 0, 0);
        }
        store_act(aa, yhi + (long)node * DIM, Y1, 136, 0, wv, lane);
        store_act(an, nb1, Y2, 136, 1, wv, lane);
    }
    __syncthreads();   // b1 (S reads done; S becomes free for S')

    // ---- P2: wave-split layer-2 (K=128) ----
    if (wv < 4) {
        // att2: 32 feats [32wv..), B = Y1; fused logit layer, no act store
        f32x4 acc[2][2];
        ZERO2(acc[0]); ZERO2(acc[1]);
#pragma unroll
        for (int kt = 0; kt < 4; ++kt) {
            const int kb = kt * 32 + kg * 8;
            bf16x8 b0 = *reinterpret_cast<const bf16x8*>(Y1 + mrow * 136 + kb);
            bf16x8 b1 = *reinterpret_cast<const bf16x8*>(Y1 + (16 + mrow) * 136 + kb);
#pragma unroll
            for (int j = 0; j < 2; ++j) {
                bf16x8 a = *reinterpret_cast<const bf16x8*>(wp + OFF_AW2 + (size_t)((kt * 8 + wv * 2 + j) * 64 + lane) * 8);
                acc[j][0] = __builtin_amdgcn_mfma_f32_16x16x32_bf16(a, b0, acc[j][0], 0, 0, 0);
                acc[j][1] = __builtin_amdgcn_mfma_f32_16x16x32_bf16(a, b1, acc[j][1], 0, 0, 0);
            }
        }
        float lp[2][4];
        lp[0][0]=lp[0][1]=lp[0][2]=lp[0][3]=0.f;
        lp[1][0]=lp[1][1]=lp[1][2]=lp[1][3]=0.f;
#pragma unroll
        for (int j = 0; j < 2; ++j) {
            const int f = wv * 32 + j * 16 + kg * 4;
            float b0 = ab2[f], b1 = ab2[f + 1], b2 = ab2[f + 2], b3 = ab2[f + 3];
            float4 w3v[4];
#pragma unroll
            for (int r = 0; r < 4; ++r)
                w3v[r] = *reinterpret_cast<const float4*>(aw3 + (f + r) * 4);
#pragma unroll
            for (int mf = 0; mf < 2; ++mf) {
                float vv[4] = {acc[j][mf][0] + b0, acc[j][mf][1] + b1,
                               acc[j][mf][2] + b2, acc[j][mf][3] + b3};
#pragma unroll
                for (int r = 0; r < 4; ++r) {
                    float v = fmaxf(vv[r], 0.f);
                    lp[mf][0] += v * w3v[r].x;
                    lp[mf][1] += v * w3v[r].y;
                    lp[mf][2] += v * w3v[r].z;
                    lp[mf][3] += v * w3v[r].w;
                }
            }
        }
#pragma unroll
        for (int mf = 0; mf < 2; ++mf)
#pragma unroll
            for (int hh = 0; hh < 4; ++hh) {
                lp[mf][hh] += __shfl_xor(lp[mf][hh], 16);
                lp[mf][hh] += __shfl_xor(lp[mf][hh], 32);
            }
        if (lane < 16) {
#pragma unroll
            for (int mf = 0; mf < 2; ++mf) {
                float4 o = make_float4(lp[mf][0], lp[mf][1], lp[mf][2], lp[mf][3]);
                *reinterpret_cast<float4*>(&sLP[wv][mf * 16 + mrow][0]) = o;
            }
        }
    } else {
        // node2: 32 feats [32(wv-4)..), B = Y2 -> gelu -> S' (stride 136, in S)
        const int w4 = wv - 4;
        f32x4 acc[2][2];
        ZERO2(acc[0]); ZERO2(acc[1]);
#pragma unroll
        for (int kt = 0; kt < 4; ++kt) {
            const int kb = kt * 32 + kg * 8;
            bf16x8 b0 = *reinterpret_cast<const bf16x8*>(Y2 + mrow * 136 + kb);
            bf16x8 b1 = *reinterpret_cast<const bf16x8*>(Y2 + (16 + mrow) * 136 + kb);
#pragma unroll
            for (int j = 0; j < 2; ++j) {
                bf16x8 a = *reinterpret_cast<const bf16x8*>(wp + OFF_NW2 + (size_t)((kt * 8 + w4 * 2 + j) * 64 + lane) * 8);
                acc[j][0] = __builtin_amdgcn_mfma_f32_16x16x32_bf16(a, b0, acc[j][0], 0, 0, 0);
                acc[j][1] = __builtin_amdgcn_mfma_f32_16x16x32_bf16(a, b1, acc[j][1], 0, 0, 0);
            }
        }
#pragma unroll
        for (int j = 0; j < 2; ++j) {
            const int f = w4 * 32 + j * 16 + kg * 4;
            float b0 = nb2[f], b1 = nb2[f + 1], b2 = nb2[f + 2], b3 = nb2[f + 3];
#pragma unroll
            for (int mf = 0; mf < 2; ++mf) {
                float vv[4] = {acc[j][mf][0] + b0, acc[j][mf][1] + b1,
                               acc[j][mf][2] + b2, acc[j][mf][3] + b3};
                bf16x4 pk;
#pragma unroll
                for (int r = 0; r < 4; ++r) pk[r] = (__bf16)gelu_f(vv[r]);
                *reinterpret_cast<bf16x4*>(S + (mf * 16 + mrow) * 136 + f) = pk;
            }
        }
    }
    __syncthreads();   // b2 (Y1/Y2 reads done; S' ready)

    // ---- P3: wave-0 softmax (reduce + normalize, wave-internal order); node3 (all waves) ----
    if (wv == 0) {
        const int m0 = lane >> 2, hh = lane & 3;   // lane holds (m0,hh) and (m0+16,hh)
        const float sc = 0.17677669529f;           // 1/sqrt(32)
        float v0 = ab3[hh], v1 = ab3[hh];
#pragma unroll
        for (int w = 0; w < 4; ++w) { v0 += sLP[w][m0][hh]; v1 += sLP[w][16 + m0][hh]; }
        v0 *= sc; v1 *= sc;
        if (16 + m0 >= KNEI) v1 = -1e30f;          // pad rows 30/31
        float mx = fmaxf(v0, v1);
#pragma unroll
        for (int msk = 4; msk <= 32; msk <<= 1) mx = fmaxf(mx, __shfl_xor(mx, msk));
        float e0 = __expf(v0 - mx), e1 = __expf(v1 - mx);   // pad -> exp(-huge) = 0
        float sm = e0 + e1;
#pragma unroll
        for (int msk = 4; msk <= 32; msk <<= 1) sm += __shfl_xor(sm, msk);
        float inv = __builtin_amdgcn_rcpf(sm);
        sW[m0][hh]      = e0 * inv;
        sW[16 + m0][hh] = e1 * inv;
    }
    f32x4 v2[2];
    ZERO2(v2);
#pragma unroll
    for (int kt = 0; kt < 4; ++kt) {
        const int kb = kt * 32 + kg * 8;
        bf16x8 b0 = *reinterpret_cast<const bf16x8*>(S + mrow * 136 + kb);
        bf16x8 b1 = *reinterpret_cast<const bf16x8*>(S + (16 + mrow) * 136 + kb);
        bf16x8 a = *reinterpret_cast<const bf16x8*>(wp + OFF_NW3 + (size_t)((kt * 8 + wv) * 64 + lane) * 8);
        v2[0] = __builtin_amdgcn_mfma_f32_16x16x32_bf16(a, b0, v2[0], 0, 0, 0);
        v2[1] = __builtin_amdgcn_mfma_f32_16x16x32_bf16(a, b1, v2[1], 0, 0, 0);
    }
    __syncthreads();   // b3 (sW visible; V in regs)

    // ---- P4: fused aggregation epilogue: pre[node][n] = sum_m w[m]*(V+nb3) ----
    {
        const int hh = wv >> 1;           // head of this wave's 16-feature slice
        float wgt0 = sW[mrow][hh];        // edge m = mrow      (mf=0)
        float wgt1 = sW[16 + mrow][hh];   // edge m = 16 + mrow (mf=1)
        float part[4];
#pragma unroll
        for (int r = 0; r < 4; ++r)
            part[r] = wgt0 * v2[0][r] + wgt1 * v2[1][r];
#pragma unroll
        for (int msk = 1; msk <= 8; msk <<= 1)
#pragma unroll
            for (int r = 0; r < 4; ++r)
                part[r] += __shfl_xor(part[r], msk);
        if (mrow == 0) {                  // lanes 0,16,32,48 -> kg 0..3
            const int nb = wv * 16 + kg * 4;
            float4 o = make_float4(part[0] + nb3[nb],     part[1] + nb3[nb + 1],
                                   part[2] + nb3[nb + 2], part[3] + nb3[nb + 3]);
            *reinterpret_cast<float4*>(pre_out + (long)node * DIM + nb) = o;
        }
    }
}

extern "C" void kernel_launch(void* const* d_in, const int* in_sizes, int n_in,
                              void* d_out, int out_size, void* d_ws, size_t ws_size,
                              hipStream_t stream) {
    const float* h   = (const float*)d_in[0];
    const float* e   = (const float*)d_in[1];
    const int*   ei  = (const int*)d_in[2];
    const float* aw1 = (const float*)d_in[3];
    const float* ab1 = (const float*)d_in[4];
    const float* aw2 = (const float*)d_in[5];
    const float* ab2 = (const float*)d_in[6];
    const float* aw3 = (const float*)d_in[7];
    const float* ab3 = (const float*)d_in[8];
    const float* nw1 = (const float*)d_in[9];
    const float* nb1 = (const float*)d_in[10];
    const float* nw2 = (const float*)d_in[11];
    const float* nb2 = (const float*)d_in[12];
    const float* nw3 = (const float*)d_in[13];
    const float* nb3 = (const float*)d_in[14];
    const float* thw = (const float*)d_in[15];
    float* out = (float*)d_out;
    __bf16* wp = (__bf16*)d_ws;
    float* yhi = (float*)((char*)d_ws + YHI_BYTE_OFF);

    // all-weight repack (f32 -> bf16 MFMA-fragment order), one launch
    repack_all<<<TOT_TILES * 2, 256, 0, stream>>>(aw1, aw2, nw1, nw2, nw3, thw, wp);

    const int nblk = (N_NODES + 63) / 64;
    // yhi = h @ att_w1[0:128,:] + ab1   (hi part of att layer 1, per node)
    mm128<<<nblk, 512, 0, stream>>>(h, yhi, wp + OFF_AW1, ab1);

    gnn_fused<<<N_NODES, 512, 0, stream>>>(h, e, ei, yhi, ab2, aw3, ab3,
                                           nb1, nb2, nb3, wp, out);
    // out = pre @ to_h_w (in-place)
    mm128<<<nblk, 512, 0, stream>>>(out, out, wp + OFF_TH, nullptr);
}

// Round 13
// 149.388 us; speedup vs baseline: 1.6399x; 1.0300x over previous
//
#include <hip/hip_runtime.h>
#include <hip/hip_bf16.h>

#define N_NODES 10000
#define KNEI    30
#define DIM     128
#define EDGES   (N_NODES * KNEI)

typedef __attribute__((ext_vector_type(4))) float  f32x4;
typedef __attribute__((ext_vector_type(8))) __bf16 bf16x8;
typedef __attribute__((ext_vector_type(4))) __bf16 bf16x4;

// packed bf16 weight offsets in d_ws (element units); per-matrix fragment tiles
// AW1 (K=384, kt0..3 = hi part, kt4..11 = e|hj), others K=128/256, Ntiles=8.
// A3 = att_w3 [128][4] zero-padded to N=16 (1 n-tile, 4 k-tiles).
#define OFF_AW1 0        // 96 tiles
#define OFF_AW2 49152    // 32 tiles
#define OFF_NW1 65536    // 64 tiles
#define OFF_NW2 98304    // 32 tiles
#define OFF_NW3 114688   // 32 tiles
#define OFF_TH  131072   // 32 tiles
#define OFF_A3  147456   // 4 tiles
#define TOT_TILES 292
#define YHI_BYTE_OFF (300 * 1024)   // f32 yhi[N][128] after weights

// Pack all weights (f32) into MFMA A-fragment order, bf16, one launch.
// tile = kt*8+nt; lane holds n = nt*16+(lane&15), k = kt*32+(lane>>4)*8+i.
__global__ __launch_bounds__(256) void repack_all(
    const float* __restrict__ aw1, const float* __restrict__ aw2,
    const float* __restrict__ nw1, const float* __restrict__ nw2,
    const float* __restrict__ nw3, const float* __restrict__ thw,
    const float* __restrict__ aw3, __bf16* __restrict__ dst) {
    int t = blockIdx.x * 256 + threadIdx.x;
    if (t >= TOT_TILES * 512) return;
    int tile = t >> 9;
    int i    = t & 7;
    int lane = (t >> 3) & 63;
    int krow = ((lane >> 4) << 3) + i;
    int ncol = lane & 15;
    float v;
    if (tile >= 288) {                   // A3: aw3 [128][4] padded to 16 cols
        int k = (tile - 288) * 32 + krow;
        v = (ncol < 4) ? aw3[k * 4 + ncol] : 0.f;
    } else {
        const float* src; int lt;
        if      (tile < 96)  { src = aw1; lt = tile; }        // K=384
        else if (tile < 128) { src = aw2; lt = tile - 96; }
        else if (tile < 192) { src = nw1; lt = tile - 128; }  // K=256
        else if (tile < 224) { src = nw2; lt = tile - 192; }
        else if (tile < 256) { src = nw3; lt = tile - 224; }
        else                 { src = thw; lt = tile - 256; }
        int nt = lt & 7;
        int kt = lt >> 3;
        v = src[(kt * 32 + krow) * DIM + nt * 16 + ncol];
    }
    dst[t] = (__bf16)v;
}

// fast gelu: 0.5x(1+tanh(u)) = x - x/(exp(2u)+1)  (~8 VALU incl native rcp)
__device__ __forceinline__ float gelu_f(float x) {
    float y = x * fmaf(0.0713548163f, x * x, 1.5957691216f);  // 2u
    float r = __builtin_amdgcn_rcpf(__expf(y) + 1.f);
    return x - x * r;
}

__device__ __forceinline__ bf16x4 cvt4(float4 v) {
    bf16x4 r;
    r[0] = (__bf16)v.x; r[1] = (__bf16)v.y; r[2] = (__bf16)v.z; r[3] = (__bf16)v.w;
    return r;
}

// actmode: 0 = relu, 1 = gelu. bias may be a per-node yhi row.
__device__ __forceinline__ void store_act(f32x4 acc[2], const float* __restrict__ bias,
                                          __bf16* y, int sy, int actmode,
                                          int wv, int lane) {
    const int mrow = lane & 15;
    const int kgrp = (lane >> 4) & 3;
    const int nb = wv * 16 + kgrp * 4;
    float b0 = bias[nb], b1 = bias[nb + 1], b2 = bias[nb + 2], b3 = bias[nb + 3];
#pragma unroll
    for (int mf = 0; mf < 2; ++mf) {
        bf16x4 pk;
        float vv[4] = {acc[mf][0] + b0, acc[mf][1] + b1, acc[mf][2] + b2, acc[mf][3] + b3};
#pragma unroll
        for (int r = 0; r < 4; ++r) {
            float v = vv[r];
            v = actmode == 0 ? fmaxf(v, 0.f) : gelu_f(v);
            pk[r] = (__bf16)v;
        }
        *reinterpret_cast<bf16x4*>(y + (mf * 16 + mrow) * sy + nb) = pk;
    }
}

#define ZERO2(A) do { A[0] = (f32x4){0.f,0.f,0.f,0.f}; A[1] = (f32x4){0.f,0.f,0.f,0.f}; } while (0)

// ---- generic 128->128 row GEMM (64 rows/block, 8 waves): out = in @ Wfrag (+bias) ----
__global__ __launch_bounds__(512) void mm128(const float* __restrict__ in,
                                             float* __restrict__ outp,
                                             const __bf16* __restrict__ wfrag,
                                             const float* __restrict__ bias) {
    __shared__ __bf16 sP[64 * 136];
    const int tid  = threadIdx.x;
    const int wv   = tid >> 6;
    const int lane = tid & 63;
    const int mrow = lane & 15;
    const int kgrp = lane >> 4;
    const int base = blockIdx.x * 64;

#pragma unroll
    for (int c = 0; c < 4; ++c) {
        int idx = c * 512 + tid;
        int m  = idx >> 5;
        int jv = idx & 31;
        int row = base + m;
        float4 v = make_float4(0.f, 0.f, 0.f, 0.f);
        if (row < N_NODES) v = *reinterpret_cast<const float4*>(in + (long)row * DIM + jv * 4);
        *reinterpret_cast<bf16x4*>(&sP[m * 136 + jv * 4]) = cvt4(v);
    }
    __syncthreads();

    f32x4 acc[4];
#pragma unroll
    for (int mf = 0; mf < 4; ++mf) acc[mf] = (f32x4){0.f, 0.f, 0.f, 0.f};
#pragma unroll
    for (int kt = 0; kt < 4; ++kt) {
        bf16x8 a = *reinterpret_cast<const bf16x8*>(wfrag + ((kt * 8 + wv) * 64 + lane) * 8);
        const int kb = kt * 32 + kgrp * 8;
#pragma unroll
        for (int mf = 0; mf < 4; ++mf) {
            bf16x8 b = *reinterpret_cast<const bf16x8*>(sP + (mf * 16 + mrow) * 136 + kb);
            acc[mf] = __builtin_amdgcn_mfma_f32_16x16x32_bf16(a, b, acc[mf], 0, 0, 0);
        }
    }
    const int nb = wv * 16 + kgrp * 4;
    float b0 = 0.f, b1 = 0.f, b2 = 0.f, b3 = 0.f;
    if (bias) { b0 = bias[nb]; b1 = bias[nb + 1]; b2 = bias[nb + 2]; b3 = bias[nb + 3]; }
#pragma unroll
    for (int mf = 0; mf < 4; ++mf) {
        int row = base + mf * 16 + mrow;
        if (row < N_NODES) {
            float4 o = make_float4(acc[mf][0] + b0, acc[mf][1] + b1,
                                   acc[mf][2] + b2, acc[mf][3] + b3);
            *reinterpret_cast<float4*>(outp + (long)row * DIM + nb) = o;
        }
    }
}

// ---- fused kernel: one block = 1 node (30 edges padded to 32), 512 thr = 8 waves ----
// 4 barriers. P1 = MERGED layer-1 (att1 + node1 share each ds_read of S).
// P2 = wave-split layer-2: waves 0-3 att2 -> relu -> A2; waves 4-7 node2 -> gelu -> S'.
// P3 = node3 (V in regs, all waves); wave 0 also: logits = A2 @ A3frag via 4 MFMA
//      (matrix pipe, replaces ~130 VALU ops/thread) + lane<16 softmax -> sW.
// P4 = fused aggregation epilogue.
// Occupancy law (r1..r12 measured): waves/SIMD ~ floor(256/VGPR), 512-thr blocks.
// VGPR 32 -> 85% occ; 36 -> 64%. Keep register peak minimal (no lp/w3v arrays).
__global__ __launch_bounds__(512, 4) void gnn_fused(
    const float* __restrict__ h, const float* __restrict__ e, const int* __restrict__ eidx,
    const float* __restrict__ yhi,
    const float* __restrict__ ab2, const float* __restrict__ ab3,
    const float* __restrict__ nb1, const float* __restrict__ nb2, const float* __restrict__ nb3,
    const __bf16* __restrict__ wp, float* __restrict__ pre_out) {

    __shared__ __bf16 S[8704];        // staging e|hj (stride 264, 8448 used);
                                      // after P1: S' = node2-out @0, A2 = att2-out @4352 (stride 136)
    __shared__ __bf16 Y1[32 * 136];   // att1-out
    __shared__ __bf16 Y2[32 * 136];   // node1-out
    __shared__ float  sW[32][4];      // softmax weights (rows 30/31 = 0)

    const int tid  = threadIdx.x;
    const int wv   = tid >> 6;
    const int lane = tid & 63;
    const int mrow = lane & 15;
    const int kg   = (lane >> 4) & 3;
    const int node = blockIdx.x;
    const long ebase = (long)node * KNEI;

    // ---- P0: stage e|hj (f32 -> bf16), pad rows 30/31 = 0 ----
#pragma unroll
    for (int c = 0; c < 2; ++c) {
        int idx = c * 512 + tid;
        int m  = idx >> 5;   // row 0..31
        int jv = idx & 31;   // float4 col
        float4 ev = make_float4(0.f, 0.f, 0.f, 0.f), hjv = ev;
        if (m < KNEI) {
            long ge = ebase + m;
            ev  = *reinterpret_cast<const float4*>(e + ge * DIM + jv * 4);
            int dstn = eidx[EDGES + ge];
            hjv = *reinterpret_cast<const float4*>(h + (long)dstn * DIM + jv * 4);
        }
        *reinterpret_cast<bf16x4*>(&S[m * 264 + jv * 4])       = cvt4(ev);
        *reinterpret_cast<bf16x4*>(&S[m * 264 + 128 + jv * 4]) = cvt4(hjv);
    }
    __syncthreads();   // b0

    // ---- P1: MERGED layer-1 (K=256): att1 & node1 share S b-reads ----
    {
        f32x4 aa[2], an[2];
        ZERO2(aa); ZERO2(an);
        const __bf16* wA = wp + OFF_AW1 + 16384;   // att_w1 e|hj part (kt 4..11)
        const __bf16* wN = wp + OFF_NW1;
#pragma unroll
        for (int kt = 0; kt < 8; ++kt) {
            const int kb = kt * 32 + kg * 8;
            bf16x8 b0 = *reinterpret_cast<const bf16x8*>(S + mrow * 264 + kb);
            bf16x8 b1 = *reinterpret_cast<const bf16x8*>(S + (16 + mrow) * 264 + kb);
            bf16x8 a0 = *reinterpret_cast<const bf16x8*>(wA + ((kt * 8 + wv) * 64 + lane) * 8);
            aa[0] = __builtin_amdgcn_mfma_f32_16x16x32_bf16(a0, b0, aa[0], 0, 0, 0);
            aa[1] = __builtin_amdgcn_mfma_f32_16x16x32_bf16(a0, b1, aa[1], 0, 0, 0);
            bf16x8 a1 = *reinterpret_cast<const bf16x8*>(wN + ((kt * 8 + wv) * 64 + lane) * 8);
            an[0] = __builtin_amdgcn_mfma_f32_16x16x32_bf16(a1, b0, an[0], 0, 0, 0);
            an[1] = __builtin_amdgcn_mfma_f32_16x16x32_bf16(a1, b1, an[1], 0, 0, 0);
        }
        store_act(aa, yhi + (long)node * DIM, Y1, 136, 0, wv, lane);
        store_act(an, nb1, Y2, 136, 1, wv, lane);
    }
    __syncthreads();   // b1 (S reads done; S free for S'/A2)

    // ---- P2: wave-split layer-2 (K=128): att2 -> A2 (relu), node2 -> S' (gelu) ----
    {
        const bool isatt = (wv < 4);
        const int w4 = isatt ? wv : (wv - 4);
        const __bf16* B = isatt ? Y1 : Y2;
        const __bf16* W = wp + (isatt ? OFF_AW2 : OFF_NW2);
        const float* bias = isatt ? ab2 : nb2;
        __bf16* dst = S + (isatt ? 4352 : 0);
        f32x4 acc[2][2];
        ZERO2(acc[0]); ZERO2(acc[1]);
#pragma unroll
        for (int kt = 0; kt < 4; ++kt) {
            const int kb = kt * 32 + kg * 8;
            bf16x8 b0 = *reinterpret_cast<const bf16x8*>(B + mrow * 136 + kb);
            bf16x8 b1 = *reinterpret_cast<const bf16x8*>(B + (16 + mrow) * 136 + kb);
#pragma unroll
            for (int j = 0; j < 2; ++j) {
                bf16x8 a = *reinterpret_cast<const bf16x8*>(W + (size_t)((kt * 8 + w4 * 2 + j) * 64 + lane) * 8);
                acc[j][0] = __builtin_amdgcn_mfma_f32_16x16x32_bf16(a, b0, acc[j][0], 0, 0, 0);
                acc[j][1] = __builtin_amdgcn_mfma_f32_16x16x32_bf16(a, b1, acc[j][1], 0, 0, 0);
            }
        }
#pragma unroll
        for (int j = 0; j < 2; ++j) {
            const int f = w4 * 32 + j * 16 + kg * 4;
            float b0 = bias[f], b1 = bias[f + 1], b2 = bias[f + 2], b3 = bias[f + 3];
#pragma unroll
            for (int mf = 0; mf < 2; ++mf) {
                float vv[4] = {acc[j][mf][0] + b0, acc[j][mf][1] + b1,
                               acc[j][mf][2] + b2, acc[j][mf][3] + b3};
                bf16x4 pk;
#pragma unroll
                for (int r = 0; r < 4; ++r) {
                    float v = isatt ? fmaxf(vv[r], 0.f) : gelu_f(vv[r]);
                    pk[r] = (__bf16)v;
                }
                *reinterpret_cast<bf16x4*>(dst + (mf * 16 + mrow) * 136 + f) = pk;
            }
        }
    }
    __syncthreads();   // b2 (Y1/Y2 reads done; S' and A2 ready)

    // ---- P3: wave 0: logits via MFMA + softmax; all waves: node3 (V in regs) ----
    if (wv == 0) {
        const __bf16* A2 = S + 4352;
        f32x4 la[2];
        ZERO2(la);
#pragma unroll
        for (int kt = 0; kt < 4; ++kt) {
            const int kb = kt * 32 + kg * 8;
            bf16x8 b0 = *reinterpret_cast<const bf16x8*>(A2 + mrow * 136 + kb);
            bf16x8 b1 = *reinterpret_cast<const bf16x8*>(A2 + (16 + mrow) * 136 + kb);
            bf16x8 a = *reinterpret_cast<const bf16x8*>(wp + OFF_A3 + ((kt * 64) + lane) * 8);
            la[0] = __builtin_amdgcn_mfma_f32_16x16x32_bf16(a, b0, la[0], 0, 0, 0);
            la[1] = __builtin_amdgcn_mfma_f32_16x16x32_bf16(a, b1, la[1], 0, 0, 0);
        }
        if (lane < 16) {   // lane = edge m; heads 0-3 in regs (kg==0 slice)
            const float sc = 0.17677669529f;   // 1/sqrt(32)
            float v0[4], v1[4], mx[4];
            const bool pad1 = (16 + lane) >= KNEI;
#pragma unroll
            for (int r = 0; r < 4; ++r) {
                v0[r] = (la[0][r] + ab3[r]) * sc;
                v1[r] = pad1 ? -1e30f : (la[1][r] + ab3[r]) * sc;
                mx[r] = fmaxf(v0[r], v1[r]);
            }
#pragma unroll
            for (int msk = 1; msk <= 8; msk <<= 1)
#pragma unroll
                for (int r = 0; r < 4; ++r) mx[r] = fmaxf(mx[r], __shfl_xor(mx[r], msk));
            float e0[4], e1[4], sm[4];
#pragma unroll
            for (int r = 0; r < 4; ++r) {
                e0[r] = __expf(v0[r] - mx[r]);
                e1[r] = __expf(v1[r] - mx[r]);   // pad -> 0
                sm[r] = e0[r] + e1[r];
            }
#pragma unroll
            for (int msk = 1; msk <= 8; msk <<= 1)
#pragma unroll
                for (int r = 0; r < 4; ++r) sm[r] += __shfl_xor(sm[r], msk);
            float4 w0, w1;
            float i0 = __builtin_amdgcn_rcpf(sm[0]), i1 = __builtin_amdgcn_rcpf(sm[1]);
            float i2 = __builtin_amdgcn_rcpf(sm[2]), i3 = __builtin_amdgcn_rcpf(sm[3]);
            w0 = make_float4(e0[0] * i0, e0[1] * i1, e0[2] * i2, e0[3] * i3);
            w1 = make_float4(e1[0] * i0, e1[1] * i1, e1[2] * i2, e1[3] * i3);
            *reinterpret_cast<float4*>(&sW[lane][0])      = w0;
            *reinterpret_cast<float4*>(&sW[16 + lane][0]) = w1;   // rows 30/31 -> 0
        }
    }
    f32x4 v2[2];
    ZERO2(v2);
#pragma unroll
    for (int kt = 0; kt < 4; ++kt) {
        const int kb = kt * 32 + kg * 8;
        bf16x8 b0 = *reinterpret_cast<const bf16x8*>(S + mrow * 136 + kb);
        bf16x8 b1 = *reinterpret_cast<const bf16x8*>(S + (16 + mrow) * 136 + kb);
        bf16x8 a = *reinterpret_cast<const bf16x8*>(wp + OFF_NW3 + (size_t)((kt * 8 + wv) * 64 + lane) * 8);
        v2[0] = __builtin_amdgcn_mfma_f32_16x16x32_bf16(a, b0, v2[0], 0, 0, 0);
        v2[1] = __builtin_amdgcn_mfma_f32_16x16x32_bf16(a, b1, v2[1], 0, 0, 0);
    }
    __syncthreads();   // b3 (sW visible; V in regs)

    // ---- P4: fused aggregation epilogue: pre[node][n] = sum_m w[m]*(V+nb3) ----
    {
        const int hh = wv >> 1;           // head of this wave's 16-feature slice
        float wgt0 = sW[mrow][hh];        // edge m = mrow      (mf=0)
        float wgt1 = sW[16 + mrow][hh];   // edge m = 16 + mrow (mf=1)
        float part[4];
#pragma unroll
        for (int r = 0; r < 4; ++r)
            part[r] = wgt0 * v2[0][r] + wgt1 * v2[1][r];
#pragma unroll
        for (int msk = 1; msk <= 8; msk <<= 1)
#pragma unroll
            for (int r = 0; r < 4; ++r)
                part[r] += __shfl_xor(part[r], msk);
        if (mrow == 0) {                  // lanes 0,16,32,48 -> kg 0..3
            const int nb = wv * 16 + kg * 4;
            float4 o = make_float4(part[0] + nb3[nb],     part[1] + nb3[nb + 1],
                                   part[2] + nb3[nb + 2], part[3] + nb3[nb + 3]);
            *reinterpret_cast<float4*>(pre_out + (long)node * DIM + nb) = o;
        }
    }
}

extern "C" void kernel_launch(void* const* d_in, const int* in_sizes, int n_in,
                              void* d_out, int out_size, void* d_ws, size_t ws_size,
                              hipStream_t stream) {
    const float* h   = (const float*)d_in[0];
    const float* e   = (const float*)d_in[1];
    const int*   ei  = (const int*)d_in[2];
    const float* aw1 = (const float*)d_in[3];
    const float* ab1 = (const float*)d_in[4];
    const float* aw2 = (const float*)d_in[5];
    const float* ab2 = (const float*)d_in[6];
    const float* aw3 = (const float*)d_in[7];
    const float* ab3 = (const float*)d_in[8];
    const float* nw1 = (const float*)d_in[9];
    const float* nb1 = (const float*)d_in[10];
    const float* nw2 = (const float*)d_in[11];
    const float* nb2 = (const float*)d_in[12];
    const float* nw3 = (const float*)d_in[13];
    const float* nb3 = (const float*)d_in[14];
    const float* thw = (const float*)d_in[15];
    float* out = (float*)d_out;
    __bf16* wp = (__bf16*)d_ws;
    float* yhi = (float*)((char*)d_ws + YHI_BYTE_OFF);

    // all-weight repack (f32 -> bf16 MFMA-fragment order), one launch
    repack_all<<<(TOT_TILES * 512 + 255) / 256, 256, 0, stream>>>(
        aw1, aw2, nw1, nw2, nw3, thw, aw3, wp);

    const int nblk = (N_NODES + 63) / 64;
    // yhi = h @ att_w1[0:128,:] + ab1   (hi part of att layer 1, per node)
    mm128<<<nblk, 512, 0, stream>>>(h, yhi, wp + OFF_AW1, ab1);

    gnn_fused<<<N_NODES, 512, 0, stream>>>(h, e, ei, yhi, ab2, ab3,
                                           nb1, nb2, nb3, wp, out);
    // out = pre @ to_h_w (in-place)
    mm128<<<nblk, 512, 0, stream>>>(out, out, wp + OFF_TH, nullptr);
}